// Round 7
// baseline (296.064 us; speedup 1.0000x reference)
//
#include <hip/hip_runtime.h>

constexpr int N_NODES = 100000;
constexpr int N_EDGES = 1600000;
constexpr int F = 128;
constexpr int H = 8;
constexpr float ALPHA = 0.2f;
constexpr float EPSF = 1e-12f;

constexpr int PSHIFT = 8;                         // 256 nodes per partition
constexpr int PN = 1 << PSHIFT;                   // 256
constexpr int NPART = (N_NODES + PN - 1) / PN;    // 391
constexpr int MAXPART = 5120;                     // mean 4096 + ~16 sigma
constexpr int EPB = 4096;                         // edges per block in pass A
constexpr int OCAP = 4096;                        // overflow list capacity

constexpr int KA_BLOCKS = (N_EDGES + EPB - 1) / EPB;   // 391
constexpr int K1_BLOCKS = (N_NODES + 1023) / 1024;     // 98

static_assert(N_EDGES % 64 == 0, "k4_hs assumes 64-edge blocks");

// Fused kA+k1: blocks [0,KA_BLOCKS) radix-partition edges; blocks
// [KA_BLOCKS, KA_BLOCKS+K1_BLOCKS) compute per-node scores. The two are
// independent -> one dispatch lets them co-schedule across CUs (kA alone is
// 391 blocks = 1.5/CU with a x1.5 tail; k1 fills the idle capacity).
__global__ void __launch_bounds__(1024)
kA1_fused(const int* __restrict__ row, const int* __restrict__ col,
          int* __restrict__ gcnt, unsigned* __restrict__ part,
          int* __restrict__ ocnt, int2* __restrict__ olist,
          const float* __restrict__ x, const float* __restrict__ aa,
          float* __restrict__ srn, float* __restrict__ sd) {
    __shared__ int hist[NPART];
    __shared__ int base[NPART];
    __shared__ float sa[H * 2 * F];   // 8 KB (k1 branch)
    const int t = threadIdx.x;

    if (blockIdx.x < KA_BLOCKS) {
        // ---------------- kA: radix partition ----------------
        const int e0 = blockIdx.x * EPB;
        constexpr int K = EPB / 1024;
        int rr[K], cc[K];
        for (int p = t; p < NPART; p += 1024) hist[p] = 0;
        __syncthreads();
#pragma unroll
        for (int k = 0; k < K; ++k) {
            int i = e0 + k * 1024 + t;
            if (i < N_EDGES) {
                rr[k] = row[i];
                cc[k] = col[i];
                atomicAdd(&hist[rr[k] >> PSHIFT], 1);
            } else rr[k] = -1;
        }
        __syncthreads();
        for (int p = t; p < NPART; p += 1024) {
            int h = hist[p];
            base[p] = h ? atomicAdd(&gcnt[p], h) : 0;
            hist[p] = 0;  // reuse as cursor
        }
        __syncthreads();
#pragma unroll
        for (int k = 0; k < K; ++k) {
            if (rr[k] >= 0) {
                int r = rr[k], c = cc[k];
                int p = r >> PSHIFT;
                int slot = base[p] + atomicAdd(&hist[p], 1);
                unsigned pk = ((unsigned)(r & (PN - 1)) << 17) | (unsigned)c;
                if (slot < MAXPART) {
                    part[(size_t)p * MAXPART + slot] = pk;
                } else {
                    int q = atomicAdd(ocnt, 1);
                    if (q < OCAP) olist[q] = make_int2(p, (int)pk);
                }
            }
        }
    } else {
        // ---------------- k1: per-node scores ----------------
        if (t < 512) reinterpret_cast<float4*>(sa)[t] =
            reinterpret_cast<const float4*>(aa)[t];
        __syncthreads();
        int node = (blockIdx.x - KA_BLOCKS) * 1024 + t;
        if (node >= N_NODES) return;
        const float4* xr = reinterpret_cast<const float4*>(x + (size_t)node * F);
        float accs[H], accd[H];
#pragma unroll
        for (int h = 0; h < H; ++h) { accs[h] = 0.f; accd[h] = 0.f; }
        for (int f4 = 0; f4 < F / 4; f4 += 4) {   // 64B line per lane per iter
            float4 xv0 = xr[f4], xv1 = xr[f4 + 1], xv2 = xr[f4 + 2], xv3 = xr[f4 + 3];
#pragma unroll
            for (int h = 0; h < H; ++h) {
                const float* ah = &sa[h * 2 * F + 4 * f4];
                const float* bh = &sa[h * 2 * F + F + 4 * f4];
                float4 a0 = *reinterpret_cast<const float4*>(ah);
                float4 a1 = *reinterpret_cast<const float4*>(ah + 4);
                float4 a2 = *reinterpret_cast<const float4*>(ah + 8);
                float4 a3 = *reinterpret_cast<const float4*>(ah + 12);
                accs[h] += xv0.x * a0.x + xv0.y * a0.y + xv0.z * a0.z + xv0.w * a0.w
                         + xv1.x * a1.x + xv1.y * a1.y + xv1.z * a1.z + xv1.w * a1.w
                         + xv2.x * a2.x + xv2.y * a2.y + xv2.z * a2.z + xv2.w * a2.w
                         + xv3.x * a3.x + xv3.y * a3.y + xv3.z * a3.z + xv3.w * a3.w;
                float4 b0 = *reinterpret_cast<const float4*>(bh);
                float4 b1 = *reinterpret_cast<const float4*>(bh + 4);
                float4 b2 = *reinterpret_cast<const float4*>(bh + 8);
                float4 b3 = *reinterpret_cast<const float4*>(bh + 12);
                accd[h] += xv0.x * b0.x + xv0.y * b0.y + xv0.z * b0.z + xv0.w * b0.w
                         + xv1.x * b1.x + xv1.y * b1.y + xv1.z * b1.z + xv1.w * b1.w
                         + xv2.x * b2.x + xv2.y * b2.y + xv2.z * b2.z + xv2.w * b2.w
                         + xv3.x * b3.x + xv3.y * b3.y + xv3.z * b3.z + xv3.w * b3.w;
            }
        }
        float4* os = reinterpret_cast<float4*>(srn + (size_t)node * 16);
        os[0] = make_float4(accs[0], accs[1], accs[2], accs[3]);
        os[1] = make_float4(accs[4], accs[5], accs[6], accs[7]);
        float4* od = reinterpret_cast<float4*>(sd + (size_t)node * H);
        od[0] = make_float4(accd[0], accd[1], accd[2], accd[3]);
        od[1] = make_float4(accd[4], accd[5], accd[6], accd[7]);
    }
}

// Pass B: atomic-free counting-sort reduce. R7: single-wave shfl_up scan
// (1 barrier) replaces the 8-round/16-barrier Hillis-Steele; cur computed
// in-lane. Walk keeps x4 batching (VGPR <= 64 preserves 2 blocks/CU).
__global__ void __launch_bounds__(1024)
kB_sum(const float* __restrict__ sd, const unsigned* __restrict__ part,
       const int* __restrict__ gcnt, const int* __restrict__ ocnt,
       const int2* __restrict__ olist, float* __restrict__ srn) {
    __shared__ unsigned plist[MAXPART];     // 20 KB
    __shared__ unsigned sorted_c[MAXPART];  // 20 KB
    __shared__ int hist[PN];
    __shared__ int off[PN + 1];
    __shared__ int cur[PN];
    __shared__ float ssrc[PN * H];          // 8 KB
    const int p = blockIdx.x;
    const int t = threadIdx.x;
    const int nbase = p << PSHIFT;

    for (int i = t; i < PN; i += 1024) hist[i] = 0;
    for (int j = t; j < PN * H; j += 1024) {
        int n = nbase + (j >> 3);
        ssrc[j] = (n < N_NODES) ? srn[(size_t)n * 16 + (j & 7)] : 0.f;
    }
    __syncthreads();

    int cnt = gcnt[p]; if (cnt > MAXPART) cnt = MAXPART;
    const unsigned* pp = part + (size_t)p * MAXPART;

    // 1. stage + histogram
    for (int i = t; i < cnt; i += 1024) {
        unsigned pk = pp[i];
        plist[i] = pk;
        atomicAdd(&hist[pk >> 17], 1);
    }
    __syncthreads();

    // 2. single-wave inclusive scan: lane l owns hist[4l..4l+3]
    if (t < 64) {
        int h0 = hist[4 * t], h1 = hist[4 * t + 1];
        int h2 = hist[4 * t + 2], h3 = hist[4 * t + 3];
        int s0 = h0, s1 = s0 + h1, s2 = s1 + h2, s3 = s2 + h3;
        int sc = s3;
#pragma unroll
        for (int d = 1; d < 64; d <<= 1) {
            int v = __shfl_up(sc, d);
            if (t >= d) sc += v;
        }
        int prefix = sc - s3;                 // exclusive prefix of this lane
        off[4 * t + 1] = prefix + s0; off[4 * t + 2] = prefix + s1;
        off[4 * t + 3] = prefix + s2; off[4 * t + 4] = prefix + s3;
        cur[4 * t]     = prefix;      cur[4 * t + 1] = prefix + s0;
        cur[4 * t + 2] = prefix + s1; cur[4 * t + 3] = prefix + s2;
        if (t == 0) off[0] = 0;
    }
    __syncthreads();

    // 3. scatter col into segment-sorted order
    for (int i = t; i < cnt; i += 1024) {
        unsigned pk = plist[i];
        int rl = (int)(pk >> 17);
        int slot = atomicAdd(&cur[rl], 1);
        sorted_c[slot] = pk & 0x1FFFFu;
    }
    __syncthreads();

    // 4. register-accumulate per (node, pair), x4-batched; no atomics
    int mo = *ocnt; if (mo > OCAP) mo = OCAP;
    {
        int nl = t >> 2, pi = t & 3;        // PN*NPAIR == 1024 exactly
        int node = nbase + nl;
        int k0 = off[nl], k1e = off[nl + 1];
        float s0 = ssrc[nl * 8 + 2 * pi];
        float s1 = ssrc[nl * 8 + 2 * pi + 1];
        float a0 = 0.f, a1 = 0.f;
        int k = k0;
        for (; k + 4 <= k1e; k += 4) {
            int c0 = (int)sorted_c[k],     c1 = (int)sorted_c[k + 1];
            int c2 = (int)sorted_c[k + 2], c3 = (int)sorted_c[k + 3];
            float2 d0 = *reinterpret_cast<const float2*>(&sd[(size_t)c0 * H + 2 * pi]);
            float2 d1 = *reinterpret_cast<const float2*>(&sd[(size_t)c1 * H + 2 * pi]);
            float2 d2 = *reinterpret_cast<const float2*>(&sd[(size_t)c2 * H + 2 * pi]);
            float2 d3 = *reinterpret_cast<const float2*>(&sd[(size_t)c3 * H + 2 * pi]);
            float e;
            e = s0 + d0.x; e = e > 0.f ? e : ALPHA * e; a0 += __expf(e);
            e = s1 + d0.y; e = e > 0.f ? e : ALPHA * e; a1 += __expf(e);
            e = s0 + d1.x; e = e > 0.f ? e : ALPHA * e; a0 += __expf(e);
            e = s1 + d1.y; e = e > 0.f ? e : ALPHA * e; a1 += __expf(e);
            e = s0 + d2.x; e = e > 0.f ? e : ALPHA * e; a0 += __expf(e);
            e = s1 + d2.y; e = e > 0.f ? e : ALPHA * e; a1 += __expf(e);
            e = s0 + d3.x; e = e > 0.f ? e : ALPHA * e; a0 += __expf(e);
            e = s1 + d3.y; e = e > 0.f ? e : ALPHA * e; a1 += __expf(e);
        }
        for (; k < k1e; ++k) {
            int c = (int)sorted_c[k];
            float2 d = *reinterpret_cast<const float2*>(&sd[(size_t)c * H + 2 * pi]);
            float e0 = s0 + d.x; e0 = e0 > 0.f ? e0 : ALPHA * e0;
            float e1 = s1 + d.y; e1 = e1 > 0.f ? e1 : ALPHA * e1;
            a0 += __expf(e0); a1 += __expf(e1);
        }
        for (int j = 0; j < mo; ++j) {      // overflow edges (expected: none)
            int2 oe = olist[j];
            if (oe.x == p && (int)(((unsigned)oe.y) >> 17) == nl) {
                int c = oe.y & 0x1FFFF;
                float2 d = *reinterpret_cast<const float2*>(&sd[(size_t)c * H + 2 * pi]);
                float e0 = s0 + d.x; e0 = e0 > 0.f ? e0 : ALPHA * e0;
                float e1 = s1 + d.y; e1 = e1 > 0.f ? e1 : ALPHA * e1;
                a0 += __expf(e0); a1 += __expf(e1);
            }
        }
        if (node < N_NODES) {
            srn[(size_t)node * 16 + 8 + 2 * pi]     = 1.f / (a0 + EPSF);
            srn[(size_t)node * 16 + 8 + 2 * pi + 1] = 1.f / (a1 + EPSF);
        }
    }
}

// K4 head-split (R5 best, 49.0 us — at the edge-order byte floor):
// 8 lanes per edge, lane h owns head h; gathers are 32B-segment coalesced,
// results staged via LDS and stored fully coalesced.
__global__ void __launch_bounds__(512)
k4_hs(const int* __restrict__ row, const int* __restrict__ col,
      const float* __restrict__ srn, const float* __restrict__ sd,
      float* __restrict__ out) {
    __shared__ int ridx[64], cidx[64];
    __shared__ float sm[8][72];
    const int e0 = blockIdx.x * 64;
    const int t = threadIdx.x;
    if (t < 64) ridx[t] = row[e0 + t];
    else if (t < 128) cidx[t - 64] = col[e0 + t - 64];
    __syncthreads();
    {
        int el = t >> 3, h = t & 7;
        int r = ridx[el], c = cidx[el];
        float s  = srn[(size_t)r * 16 + h];
        float rv = srn[(size_t)r * 16 + 8 + h];
        float d  = sd[(size_t)c * H + h];
        float e = s + d;
        e = e > 0.f ? e : ALPHA * e;
        sm[h][el] = __expf(e) * rv;
    }
    __syncthreads();
    {
        int h2 = t >> 6, j = t & 63;
        out[(size_t)h2 * N_EDGES + e0 + j] = sm[h2][j];
    }
}

// ---------------- atomic fallback (tiny ws) ----------------
__global__ void k1_scores(const float* __restrict__ x, const float* __restrict__ aa,
                          float* __restrict__ srn, float* __restrict__ sd) {
    __shared__ float sa[H * 2 * F];
    for (int i = threadIdx.x; i < H * 2 * F; i += blockDim.x) sa[i] = aa[i];
    __syncthreads();
    int node = blockIdx.x * blockDim.x + threadIdx.x;
    if (node >= N_NODES) return;
    const float4* xr = reinterpret_cast<const float4*>(x + (size_t)node * F);
    float accs[H], accd[H];
#pragma unroll
    for (int h = 0; h < H; ++h) { accs[h] = 0.f; accd[h] = 0.f; }
    for (int f4 = 0; f4 < F / 4; ++f4) {
        float4 xv = xr[f4];
#pragma unroll
        for (int h = 0; h < H; ++h) {
            float4 av = *reinterpret_cast<const float4*>(&sa[h * 2 * F + 4 * f4]);
            float4 bv = *reinterpret_cast<const float4*>(&sa[h * 2 * F + F + 4 * f4]);
            accs[h] += xv.x * av.x + xv.y * av.y + xv.z * av.z + xv.w * av.w;
            accd[h] += xv.x * bv.x + xv.y * bv.y + xv.z * bv.z + xv.w * bv.w;
        }
    }
    float4* os = reinterpret_cast<float4*>(srn + (size_t)node * 16);
    os[0] = make_float4(accs[0], accs[1], accs[2], accs[3]);
    os[1] = make_float4(accs[4], accs[5], accs[6], accs[7]);
    float4* od = reinterpret_cast<float4*>(sd + (size_t)node * H);
    od[0] = make_float4(accd[0], accd[1], accd[2], accd[3]);
    od[1] = make_float4(accd[4], accd[5], accd[6], accd[7]);
}

__global__ void kz_zero_sums(float* __restrict__ srn) {
    int t = blockIdx.x * blockDim.x + threadIdx.x;
    if (t >= N_NODES * H) return;
    srn[(size_t)(t >> 3) * 16 + 8 + (t & 7)] = 0.f;
}

__global__ void k3nm_sum(const float* __restrict__ srn_ro, const float* __restrict__ s_dst,
                         const int* __restrict__ row, const int* __restrict__ col,
                         float* __restrict__ srn) {
    int i = blockIdx.x * blockDim.x + threadIdx.x;
    if (i >= N_EDGES) return;
    int r = row[i], c = col[i];
    const float4* sr = reinterpret_cast<const float4*>(srn_ro + (size_t)r * 16);
    float4 a0 = sr[0], a1 = sr[1];
    const float4* sc = reinterpret_cast<const float4*>(s_dst + (size_t)c * H);
    float4 b0 = sc[0], b1 = sc[1];
    float ev[H] = {a0.x + b0.x, a0.y + b0.y, a0.z + b0.z, a0.w + b0.w,
                   a1.x + b1.x, a1.y + b1.y, a1.z + b1.z, a1.w + b1.w};
#pragma unroll
    for (int h = 0; h < H; ++h) {
        float e = ev[h] > 0.f ? ev[h] : ALPHA * ev[h];
        atomicAdd(&srn[(size_t)r * 16 + 8 + h], __expf(e));
    }
}

__global__ void k_inv(float* __restrict__ srn) {
    int t = blockIdx.x * blockDim.x + threadIdx.x;
    if (t >= N_NODES * H) return;
    int n = t >> 3, h = t & 7;
    float s = srn[(size_t)n * 16 + 8 + h];
    srn[(size_t)n * 16 + 8 + h] = 1.0f / (s + EPSF);
}

__global__ void k4_out(const int* __restrict__ row, const int* __restrict__ col,
                       const float* __restrict__ srn, const float* __restrict__ s_dst,
                       float* __restrict__ out) {
    int i = blockIdx.x * blockDim.x + threadIdx.x;
    if (i >= N_EDGES) return;
    int r = row[i], c = col[i];
    const float4* sr = reinterpret_cast<const float4*>(srn + (size_t)r * 16);
    float4 a0 = sr[0], a1 = sr[1], r0 = sr[2], r1 = sr[3];
    const float4* sc = reinterpret_cast<const float4*>(s_dst + (size_t)c * H);
    float4 b0 = sc[0], b1 = sc[1];
    float ev[H] = {a0.x + b0.x, a0.y + b0.y, a0.z + b0.z, a0.w + b0.w,
                   a1.x + b1.x, a1.y + b1.y, a1.z + b1.z, a1.w + b1.w};
    float rv[H] = {r0.x, r0.y, r0.z, r0.w, r1.x, r1.y, r1.z, r1.w};
#pragma unroll
    for (int h = 0; h < H; ++h) {
        float e = ev[h] > 0.f ? ev[h] : ALPHA * ev[h];
        out[(size_t)h * N_EDGES + i] = __expf(e) * rv[h];
    }
}

extern "C" void kernel_launch(void* const* d_in, const int* in_sizes, int n_in,
                              void* d_out, int out_size, void* d_ws, size_t ws_size,
                              hipStream_t stream) {
    const float* x   = (const float*)d_in[0];
    const int*   row = (const int*)d_in[1];
    const int*   col = (const int*)d_in[2];
    const float* aa  = (const float*)d_in[3];
    float* out = (float*)d_out;

    // ws layout: srn [N][16] | sd [N][8] | part | gcnt | ocnt(16) | olist
    float*    srn  = (float*)d_ws;
    float*    sd   = srn + (size_t)N_NODES * 16;
    unsigned* part = (unsigned*)(sd + (size_t)N_NODES * H);
    int*      gcnt = (int*)(part + (size_t)NPART * MAXPART);
    int*      ocnt = gcnt + NPART;
    int2*     olist = (int2*)(ocnt + 16);

    const size_t need_b = ((size_t)N_NODES * 24 + (size_t)NPART * MAXPART
                           + NPART + 16 + 2 * OCAP) * 4;  // ~17.7 MB

    const int B = 256;
    const int GE = (N_EDGES + B - 1) / B;
    const int GN = (N_NODES + B - 1) / B;

    if (ws_size >= need_b) {
        hipMemsetAsync(gcnt, 0, (size_t)(NPART + 16) * sizeof(int), stream);
        kA1_fused<<<KA_BLOCKS + K1_BLOCKS, 1024, 0, stream>>>(
            row, col, gcnt, part, ocnt, olist, x, aa, srn, sd);
        kB_sum<<<NPART, 1024, 0, stream>>>(sd, part, gcnt, ocnt, olist, srn);
        k4_hs<<<N_EDGES / 64, 512, 0, stream>>>(row, col, srn, sd, out);
    } else {
        k1_scores<<<GN, B, 0, stream>>>(x, aa, srn, sd);
        kz_zero_sums<<<(N_NODES * H + B - 1) / B, B, 0, stream>>>(srn);
        k3nm_sum<<<GE, B, 0, stream>>>(srn, sd, row, col, srn);
        k_inv<<<(N_NODES * H + B - 1) / B, B, 0, stream>>>(srn);
        k4_out<<<GE, B, 0, stream>>>(row, col, srn, sd, out);
    }
}

// Round 8
// 211.171 us; speedup vs baseline: 1.4020x; 1.4020x over previous
//
#include <hip/hip_runtime.h>

constexpr int N_NODES = 100000;
constexpr int N_EDGES = 1600000;
constexpr int F = 128;
constexpr int H = 8;
constexpr float ALPHA = 0.2f;
constexpr float EPSF = 1e-12f;

constexpr int PSHIFT = 8;                         // 256 nodes per partition
constexpr int PN = 1 << PSHIFT;                   // 256
constexpr int NPART = (N_NODES + PN - 1) / PN;    // 391
constexpr int MAXPART = 5120;                     // mean 4096 + ~16 sigma
constexpr int EPB = 4096;                         // edges per block in pass A
constexpr int OCAP = 4096;                        // overflow list capacity

constexpr int KA_BLOCKS = (N_EDGES + EPB - 1) / EPB;   // 391
constexpr int K1_BLOCKS = (N_NODES + 1023) / 1024;     // 98

static_assert(N_EDGES % 64 == 0, "k4_hs assumes 64-edge blocks");

// Fused kA+k1 (R8: spill-free). Blocks [0,KA_BLOCKS) radix-partition edges;
// blocks [KA_BLOCKS, +K1_BLOCKS) compute per-node scores with the SIMPLE
// float4-per-iter body (~50 VGPR, no spill — R7's x4 unroll spilled at the
// 1024-thread register budget: WRITE_SIZE 112 MB of scratch). At VGPR<=64 +
// 11.7 KB LDS, 2 blocks/CU -> all 489 blocks co-resident -> true overlap.
__global__ void __launch_bounds__(1024)
kA1_fused(const int* __restrict__ row, const int* __restrict__ col,
          int* __restrict__ gcnt, unsigned* __restrict__ part,
          int* __restrict__ ocnt, int2* __restrict__ olist,
          const float* __restrict__ x, const float* __restrict__ aa,
          float* __restrict__ srn, float* __restrict__ sd) {
    __shared__ int hist[NPART];
    __shared__ int base[NPART];
    __shared__ float sa[H * 2 * F];   // 8 KB (k1 branch)
    const int t = threadIdx.x;

    if (blockIdx.x < KA_BLOCKS) {
        // ---------------- kA: radix partition ----------------
        const int e0 = blockIdx.x * EPB;
        constexpr int K = EPB / 1024;
        int rr[K], cc[K];
        for (int p = t; p < NPART; p += 1024) hist[p] = 0;
        __syncthreads();
#pragma unroll
        for (int k = 0; k < K; ++k) {
            int i = e0 + k * 1024 + t;
            if (i < N_EDGES) {
                rr[k] = row[i];
                cc[k] = col[i];
                atomicAdd(&hist[rr[k] >> PSHIFT], 1);
            } else rr[k] = -1;
        }
        __syncthreads();
        for (int p = t; p < NPART; p += 1024) {
            int h = hist[p];
            base[p] = h ? atomicAdd(&gcnt[p], h) : 0;
            hist[p] = 0;  // reuse as cursor
        }
        __syncthreads();
#pragma unroll
        for (int k = 0; k < K; ++k) {
            if (rr[k] >= 0) {
                int r = rr[k], c = cc[k];
                int p = r >> PSHIFT;
                int slot = base[p] + atomicAdd(&hist[p], 1);
                unsigned pk = ((unsigned)(r & (PN - 1)) << 17) | (unsigned)c;
                if (slot < MAXPART) {
                    part[(size_t)p * MAXPART + slot] = pk;
                } else {
                    int q = atomicAdd(ocnt, 1);
                    if (q < OCAP) olist[q] = make_int2(p, (int)pk);
                }
            }
        }
    } else {
        // ---------------- k1: per-node scores (simple body) ----------------
        if (t < 512) reinterpret_cast<float4*>(sa)[t] =
            reinterpret_cast<const float4*>(aa)[t];
        __syncthreads();
        int node = (blockIdx.x - KA_BLOCKS) * 1024 + t;
        if (node >= N_NODES) return;
        const float4* xr = reinterpret_cast<const float4*>(x + (size_t)node * F);
        float accs[H], accd[H];
#pragma unroll
        for (int h = 0; h < H; ++h) { accs[h] = 0.f; accd[h] = 0.f; }
        for (int f4 = 0; f4 < F / 4; ++f4) {
            float4 xv = xr[f4];
#pragma unroll
            for (int h = 0; h < H; ++h) {
                float4 av = *reinterpret_cast<const float4*>(&sa[h * 2 * F + 4 * f4]);
                float4 bv = *reinterpret_cast<const float4*>(&sa[h * 2 * F + F + 4 * f4]);
                accs[h] += xv.x * av.x + xv.y * av.y + xv.z * av.z + xv.w * av.w;
                accd[h] += xv.x * bv.x + xv.y * bv.y + xv.z * bv.z + xv.w * bv.w;
            }
        }
        float4* os = reinterpret_cast<float4*>(srn + (size_t)node * 16);
        os[0] = make_float4(accs[0], accs[1], accs[2], accs[3]);
        os[1] = make_float4(accs[4], accs[5], accs[6], accs[7]);
        float4* od = reinterpret_cast<float4*>(sd + (size_t)node * H);
        od[0] = make_float4(accd[0], accd[1], accd[2], accd[3]);
        od[1] = make_float4(accd[4], accd[5], accd[6], accd[7]);
    }
}

// Pass B: atomic-free counting-sort reduce; single-wave shfl_up scan
// (1 barrier); x4-batched register-accumulate walk.
__global__ void __launch_bounds__(1024)
kB_sum(const float* __restrict__ sd, const unsigned* __restrict__ part,
       const int* __restrict__ gcnt, const int* __restrict__ ocnt,
       const int2* __restrict__ olist, float* __restrict__ srn) {
    __shared__ unsigned plist[MAXPART];     // 20 KB
    __shared__ unsigned sorted_c[MAXPART];  // 20 KB
    __shared__ int hist[PN];
    __shared__ int off[PN + 1];
    __shared__ int cur[PN];
    __shared__ float ssrc[PN * H];          // 8 KB
    const int p = blockIdx.x;
    const int t = threadIdx.x;
    const int nbase = p << PSHIFT;

    for (int i = t; i < PN; i += 1024) hist[i] = 0;
    for (int j = t; j < PN * H; j += 1024) {
        int n = nbase + (j >> 3);
        ssrc[j] = (n < N_NODES) ? srn[(size_t)n * 16 + (j & 7)] : 0.f;
    }
    __syncthreads();

    int cnt = gcnt[p]; if (cnt > MAXPART) cnt = MAXPART;
    const unsigned* pp = part + (size_t)p * MAXPART;

    // 1. stage + histogram
    for (int i = t; i < cnt; i += 1024) {
        unsigned pk = pp[i];
        plist[i] = pk;
        atomicAdd(&hist[pk >> 17], 1);
    }
    __syncthreads();

    // 2. single-wave inclusive scan: lane l owns hist[4l..4l+3]
    if (t < 64) {
        int h0 = hist[4 * t], h1 = hist[4 * t + 1];
        int h2 = hist[4 * t + 2], h3 = hist[4 * t + 3];
        int s0 = h0, s1 = s0 + h1, s2 = s1 + h2, s3 = s2 + h3;
        int sc = s3;
#pragma unroll
        for (int d = 1; d < 64; d <<= 1) {
            int v = __shfl_up(sc, d);
            if (t >= d) sc += v;
        }
        int prefix = sc - s3;                 // exclusive prefix of this lane
        off[4 * t + 1] = prefix + s0; off[4 * t + 2] = prefix + s1;
        off[4 * t + 3] = prefix + s2; off[4 * t + 4] = prefix + s3;
        cur[4 * t]     = prefix;      cur[4 * t + 1] = prefix + s0;
        cur[4 * t + 2] = prefix + s1; cur[4 * t + 3] = prefix + s2;
        if (t == 0) off[0] = 0;
    }
    __syncthreads();

    // 3. scatter col into segment-sorted order
    for (int i = t; i < cnt; i += 1024) {
        unsigned pk = plist[i];
        int rl = (int)(pk >> 17);
        int slot = atomicAdd(&cur[rl], 1);
        sorted_c[slot] = pk & 0x1FFFFu;
    }
    __syncthreads();

    // 4. register-accumulate per (node, pair), x4-batched; no atomics
    int mo = *ocnt; if (mo > OCAP) mo = OCAP;
    {
        int nl = t >> 2, pi = t & 3;        // PN*NPAIR == 1024 exactly
        int node = nbase + nl;
        int k0 = off[nl], k1e = off[nl + 1];
        float s0 = ssrc[nl * 8 + 2 * pi];
        float s1 = ssrc[nl * 8 + 2 * pi + 1];
        float a0 = 0.f, a1 = 0.f;
        int k = k0;
        for (; k + 4 <= k1e; k += 4) {
            int c0 = (int)sorted_c[k],     c1 = (int)sorted_c[k + 1];
            int c2 = (int)sorted_c[k + 2], c3 = (int)sorted_c[k + 3];
            float2 d0 = *reinterpret_cast<const float2*>(&sd[(size_t)c0 * H + 2 * pi]);
            float2 d1 = *reinterpret_cast<const float2*>(&sd[(size_t)c1 * H + 2 * pi]);
            float2 d2 = *reinterpret_cast<const float2*>(&sd[(size_t)c2 * H + 2 * pi]);
            float2 d3 = *reinterpret_cast<const float2*>(&sd[(size_t)c3 * H + 2 * pi]);
            float e;
            e = s0 + d0.x; e = e > 0.f ? e : ALPHA * e; a0 += __expf(e);
            e = s1 + d0.y; e = e > 0.f ? e : ALPHA * e; a1 += __expf(e);
            e = s0 + d1.x; e = e > 0.f ? e : ALPHA * e; a0 += __expf(e);
            e = s1 + d1.y; e = e > 0.f ? e : ALPHA * e; a1 += __expf(e);
            e = s0 + d2.x; e = e > 0.f ? e : ALPHA * e; a0 += __expf(e);
            e = s1 + d2.y; e = e > 0.f ? e : ALPHA * e; a1 += __expf(e);
            e = s0 + d3.x; e = e > 0.f ? e : ALPHA * e; a0 += __expf(e);
            e = s1 + d3.y; e = e > 0.f ? e : ALPHA * e; a1 += __expf(e);
        }
        for (; k < k1e; ++k) {
            int c = (int)sorted_c[k];
            float2 d = *reinterpret_cast<const float2*>(&sd[(size_t)c * H + 2 * pi]);
            float e0 = s0 + d.x; e0 = e0 > 0.f ? e0 : ALPHA * e0;
            float e1 = s1 + d.y; e1 = e1 > 0.f ? e1 : ALPHA * e1;
            a0 += __expf(e0); a1 += __expf(e1);
        }
        for (int j = 0; j < mo; ++j) {      // overflow edges (expected: none)
            int2 oe = olist[j];
            if (oe.x == p && (int)(((unsigned)oe.y) >> 17) == nl) {
                int c = oe.y & 0x1FFFF;
                float2 d = *reinterpret_cast<const float2*>(&sd[(size_t)c * H + 2 * pi]);
                float e0 = s0 + d.x; e0 = e0 > 0.f ? e0 : ALPHA * e0;
                float e1 = s1 + d.y; e1 = e1 > 0.f ? e1 : ALPHA * e1;
                a0 += __expf(e0); a1 += __expf(e1);
            }
        }
        if (node < N_NODES) {
            srn[(size_t)node * 16 + 8 + 2 * pi]     = 1.f / (a0 + EPSF);
            srn[(size_t)node * 16 + 8 + 2 * pi + 1] = 1.f / (a1 + EPSF);
        }
    }
}

// K4 head-split (R5 best, ~49 us — at the edge-order byte floor):
// 8 lanes per edge, lane h owns head h; gathers are 32B-segment coalesced,
// results staged via LDS and stored fully coalesced.
__global__ void __launch_bounds__(512)
k4_hs(const int* __restrict__ row, const int* __restrict__ col,
      const float* __restrict__ srn, const float* __restrict__ sd,
      float* __restrict__ out) {
    __shared__ int ridx[64], cidx[64];
    __shared__ float sm[8][72];
    const int e0 = blockIdx.x * 64;
    const int t = threadIdx.x;
    if (t < 64) ridx[t] = row[e0 + t];
    else if (t < 128) cidx[t - 64] = col[e0 + t - 64];
    __syncthreads();
    {
        int el = t >> 3, h = t & 7;
        int r = ridx[el], c = cidx[el];
        float s  = srn[(size_t)r * 16 + h];
        float rv = srn[(size_t)r * 16 + 8 + h];
        float d  = sd[(size_t)c * H + h];
        float e = s + d;
        e = e > 0.f ? e : ALPHA * e;
        sm[h][el] = __expf(e) * rv;
    }
    __syncthreads();
    {
        int h2 = t >> 6, j = t & 63;
        out[(size_t)h2 * N_EDGES + e0 + j] = sm[h2][j];
    }
}

// ---------------- atomic fallback (tiny ws) ----------------
__global__ void k1_scores(const float* __restrict__ x, const float* __restrict__ aa,
                          float* __restrict__ srn, float* __restrict__ sd) {
    __shared__ float sa[H * 2 * F];
    for (int i = threadIdx.x; i < H * 2 * F; i += blockDim.x) sa[i] = aa[i];
    __syncthreads();
    int node = blockIdx.x * blockDim.x + threadIdx.x;
    if (node >= N_NODES) return;
    const float4* xr = reinterpret_cast<const float4*>(x + (size_t)node * F);
    float accs[H], accd[H];
#pragma unroll
    for (int h = 0; h < H; ++h) { accs[h] = 0.f; accd[h] = 0.f; }
    for (int f4 = 0; f4 < F / 4; ++f4) {
        float4 xv = xr[f4];
#pragma unroll
        for (int h = 0; h < H; ++h) {
            float4 av = *reinterpret_cast<const float4*>(&sa[h * 2 * F + 4 * f4]);
            float4 bv = *reinterpret_cast<const float4*>(&sa[h * 2 * F + F + 4 * f4]);
            accs[h] += xv.x * av.x + xv.y * av.y + xv.z * av.z + xv.w * av.w;
            accd[h] += xv.x * bv.x + xv.y * bv.y + xv.z * bv.z + xv.w * bv.w;
        }
    }
    float4* os = reinterpret_cast<float4*>(srn + (size_t)node * 16);
    os[0] = make_float4(accs[0], accs[1], accs[2], accs[3]);
    os[1] = make_float4(accs[4], accs[5], accs[6], accs[7]);
    float4* od = reinterpret_cast<float4*>(sd + (size_t)node * H);
    od[0] = make_float4(accd[0], accd[1], accd[2], accd[3]);
    od[1] = make_float4(accd[4], accd[5], accd[6], accd[7]);
}

__global__ void kz_zero_sums(float* __restrict__ srn) {
    int t = blockIdx.x * blockDim.x + threadIdx.x;
    if (t >= N_NODES * H) return;
    srn[(size_t)(t >> 3) * 16 + 8 + (t & 7)] = 0.f;
}

__global__ void k3nm_sum(const float* __restrict__ srn_ro, const float* __restrict__ s_dst,
                         const int* __restrict__ row, const int* __restrict__ col,
                         float* __restrict__ srn) {
    int i = blockIdx.x * blockDim.x + threadIdx.x;
    if (i >= N_EDGES) return;
    int r = row[i], c = col[i];
    const float4* sr = reinterpret_cast<const float4*>(srn_ro + (size_t)r * 16);
    float4 a0 = sr[0], a1 = sr[1];
    const float4* sc = reinterpret_cast<const float4*>(s_dst + (size_t)c * H);
    float4 b0 = sc[0], b1 = sc[1];
    float ev[H] = {a0.x + b0.x, a0.y + b0.y, a0.z + b0.z, a0.w + b0.w,
                   a1.x + b1.x, a1.y + b1.y, a1.z + b1.z, a1.w + b1.w};
#pragma unroll
    for (int h = 0; h < H; ++h) {
        float e = ev[h] > 0.f ? ev[h] : ALPHA * ev[h];
        atomicAdd(&srn[(size_t)r * 16 + 8 + h], __expf(e));
    }
}

__global__ void k_inv(float* __restrict__ srn) {
    int t = blockIdx.x * blockDim.x + threadIdx.x;
    if (t >= N_NODES * H) return;
    int n = t >> 3, h = t & 7;
    float s = srn[(size_t)n * 16 + 8 + h];
    srn[(size_t)n * 16 + 8 + h] = 1.0f / (s + EPSF);
}

__global__ void k4_out(const int* __restrict__ row, const int* __restrict__ col,
                       const float* __restrict__ srn, const float* __restrict__ s_dst,
                       float* __restrict__ out) {
    int i = blockIdx.x * blockDim.x + threadIdx.x;
    if (i >= N_EDGES) return;
    int r = row[i], c = col[i];
    const float4* sr = reinterpret_cast<const float4*>(srn + (size_t)r * 16);
    float4 a0 = sr[0], a1 = sr[1], r0 = sr[2], r1 = sr[3];
    const float4* sc = reinterpret_cast<const float4*>(s_dst + (size_t)c * H);
    float4 b0 = sc[0], b1 = sc[1];
    float ev[H] = {a0.x + b0.x, a0.y + b0.y, a0.z + b0.z, a0.w + b0.w,
                   a1.x + b1.x, a1.y + b1.y, a1.z + b1.z, a1.w + b1.w};
    float rv[H] = {r0.x, r0.y, r0.z, r0.w, r1.x, r1.y, r1.z, r1.w};
#pragma unroll
    for (int h = 0; h < H; ++h) {
        float e = ev[h] > 0.f ? ev[h] : ALPHA * ev[h];
        out[(size_t)h * N_EDGES + i] = __expf(e) * rv[h];
    }
}

extern "C" void kernel_launch(void* const* d_in, const int* in_sizes, int n_in,
                              void* d_out, int out_size, void* d_ws, size_t ws_size,
                              hipStream_t stream) {
    const float* x   = (const float*)d_in[0];
    const int*   row = (const int*)d_in[1];
    const int*   col = (const int*)d_in[2];
    const float* aa  = (const float*)d_in[3];
    float* out = (float*)d_out;

    // ws layout: srn [N][16] | sd [N][8] | part | gcnt | ocnt(16) | olist
    float*    srn  = (float*)d_ws;
    float*    sd   = srn + (size_t)N_NODES * 16;
    unsigned* part = (unsigned*)(sd + (size_t)N_NODES * H);
    int*      gcnt = (int*)(part + (size_t)NPART * MAXPART);
    int*      ocnt = gcnt + NPART;
    int2*     olist = (int2*)(ocnt + 16);

    const size_t need_b = ((size_t)N_NODES * 24 + (size_t)NPART * MAXPART
                           + NPART + 16 + 2 * OCAP) * 4;  // ~17.7 MB

    const int B = 256;
    const int GE = (N_EDGES + B - 1) / B;
    const int GN = (N_NODES + B - 1) / B;

    if (ws_size >= need_b) {
        hipMemsetAsync(gcnt, 0, (size_t)(NPART + 16) * sizeof(int), stream);
        kA1_fused<<<KA_BLOCKS + K1_BLOCKS, 1024, 0, stream>>>(
            row, col, gcnt, part, ocnt, olist, x, aa, srn, sd);
        kB_sum<<<NPART, 1024, 0, stream>>>(sd, part, gcnt, ocnt, olist, srn);
        k4_hs<<<N_EDGES / 64, 512, 0, stream>>>(row, col, srn, sd, out);
    } else {
        k1_scores<<<GN, B, 0, stream>>>(x, aa, srn, sd);
        kz_zero_sums<<<(N_NODES * H + B - 1) / B, B, 0, stream>>>(srn);
        k3nm_sum<<<GE, B, 0, stream>>>(srn, sd, row, col, srn);
        k_inv<<<(N_NODES * H + B - 1) / B, B, 0, stream>>>(srn);
        k4_out<<<GE, B, 0, stream>>>(row, col, srn, sd, out);
    }
}